// Round 14
// baseline (869.566 us; speedup 1.0000x reference)
//
#include <hip/hip_runtime.h>
#include <math.h>

#define PLANE (512*512)

typedef short bf16x8 __attribute__((ext_vector_type(8)));
typedef float f32x4 __attribute__((ext_vector_type(4)));

// fast GELU (tanh form): gelu(x) = x * sigmoid(1.59577x + 0.071355x^3); |err vs erf| <= ~3e-4
__device__ __forceinline__ float gelu_f(float x) {
    float t2 = fmaf(x * x, 0.0713548162f, 1.5957691216f);
    float e = __expf(x * t2);
    float r = __builtin_amdgcn_rcpf(1.0f + e);
    return fmaf(-x, r, x);     // x - x/(1+e) = x * e/(1+e)
}

__device__ __forceinline__ unsigned short f2bf(float f) {
    union { float f; unsigned u; } v; v.f = f;
    unsigned r = v.u + 0x7FFFu + ((v.u >> 16) & 1u);
    return (unsigned short)(r >> 16);
}

__device__ __forceinline__ float bf2f(unsigned short u) {
    union { unsigned u; float f; } x; x.u = ((unsigned)u) << 16; return x.f;
}

__device__ __forceinline__ float ldval(const float* p, int off) { return p[off]; }
__device__ __forceinline__ float ldval(const unsigned short* p, int off) { return bf2f(p[off]); }

// ---------------- K1a: LayerNorm stats per pixel: P=rstd, Q=-mu*rstd ----------------
__global__ __launch_bounds__(256) void k_lnstats(const float* __restrict__ sc,
                                                 float* __restrict__ Pb,
                                                 float* __restrict__ Qb) {
    int p = blockIdx.x * 256 + threadIdx.x;      // 0 .. 524287
    int b = p >> 18;
    int hw = p & (PLANE - 1);
    const float* src = sc + (size_t)b * 64 * PLANE + hw;
    float sum = 0.f, sq = 0.f;
    #pragma unroll 8
    for (int c = 0; c < 64; ++c) {
        float v = src[(size_t)c * PLANE];
        sum += v; sq += v * v;
    }
    float mu = sum * (1.0f / 64.0f);
    float var = sq * (1.0f / 64.0f) - mu * mu;
    float rstd = rsqrtf(var + 1e-5f);
    Pb[p] = rstd;
    Qb[p] = -mu * rstd;
}

// ---------------- K1b: fused LN + depthwise 3x3 + BN + GELU -> packed bf16 t1 ----------------
__global__ __launch_bounds__(256) void k_dw64ln(const float* __restrict__ sc,
                                                const float* __restrict__ dww,
                                                const float* __restrict__ lnw,
                                                const float* __restrict__ lnb,
                                                const float* __restrict__ bns,
                                                const float* __restrict__ bnt,
                                                const float* __restrict__ Pb,
                                                const float* __restrict__ Qb,
                                                unsigned* __restrict__ t1b) {
    int p = blockIdx.x * 256 + threadIdx.x;      // pixel
    int b = p >> 18;
    int hw = p & (PLANE - 1);
    int h = hw >> 9, w = hw & 511;
    int tapoff[9]; float Pt[9], Qt[9], vm[9];
    const float* Pp = Pb + (size_t)b * PLANE;
    const float* Qp = Qb + (size_t)b * PLANE;
    #pragma unroll
    for (int dh = -1; dh <= 1; ++dh)
        #pragma unroll
        for (int dw = -1; dw <= 1; ++dw) {
            int k = (dh + 1) * 3 + dw + 1;
            int hh = h + dh, ww = w + dw;
            bool ok = (hh >= 0 && hh < 512 && ww >= 0 && ww < 512);
            int hc = ok ? hh : h, wc = ok ? ww : w;
            int off = hc * 512 + wc;
            tapoff[k] = off;
            vm[k] = ok ? 1.f : 0.f;
            Pt[k] = Pp[off]; Qt[k] = Qp[off];
        }
    const float* scb = sc + (size_t)b * 64 * PLANE;
    unsigned* ob = t1b + (size_t)b * 32 * PLANE + hw;
    for (int c2 = 0; c2 < 32; ++c2) {
        float g[2];
        #pragma unroll
        for (int e = 0; e < 2; ++e) {
            int c = c2 * 2 + e;
            const float* wp = dww + c * 9;
            const float* cp = scb + (size_t)c * PLANE;
            float conv = 0.f, wsum = 0.f;
            #pragma unroll
            for (int k = 0; k < 9; ++k) {
                float wv = wp[k];
                float raw = cp[tapoff[k]];
                conv = fmaf(wv, fmaf(raw, Pt[k], Qt[k]) * vm[k], conv);
                wsum = fmaf(wv, vm[k], wsum);
            }
            float a = lnw[c] * conv + lnb[c] * wsum;
            g[e] = gelu_f(a * bns[c] + bnt[c]);
        }
        unsigned r;
        asm("v_cvt_pk_bf16_f32 %0,%1,%2" : "=v"(r) : "v"(g[0]), "v"(g[1]));
        ob[(size_t)c2 * PLANE] = r;
    }
}

// ---------------- setup: pw weights W1/W2 -> bf16 ----------------
__global__ __launch_bounds__(256) void k_wsetup2(const float* __restrict__ W1,
                                                 const float* __restrict__ W2,
                                                 unsigned short* __restrict__ w1b,
                                                 unsigned short* __restrict__ w2b) {
    int tid = blockIdx.x * 256 + threadIdx.x;
    if (tid < 8192) { w1b[tid] = f2bf(W1[tid]); w2b[tid] = f2bf(W2[tid]); }
}

// ---------------- K3 v2: MFMA pw 64->128 (+bias+gelu) split; bf16 k_in, PAIRED v ----
// v stored as 64 pair-planes: uint = {ch 2p (lo16), ch 2p+1 (hi16)} bf16.
__global__ __launch_bounds__(256, 4) void k_pw2(
    const unsigned* __restrict__ t1b,
    const unsigned short* __restrict__ w1b, const float* __restrict__ b1,
    const unsigned short* __restrict__ w2b,
    const float* __restrict__ vbs, const float* __restrict__ vbt,
    unsigned short* __restrict__ k_in, unsigned* __restrict__ vp)
{
    __shared__ unsigned short vin[64][88];   // [px][ch] bf16
    __shared__ float epi[64 * 68];
    __shared__ float psl[128], ptl[128], pbl[128];
    int tid = threadIdx.x;
    if (tid < 128) { psl[tid] = vbs[tid]; ptl[tid] = vbt[tid]; pbl[tid] = b1[tid]; }
    int lane = tid & 63, wva = tid >> 6;
    int cl = lane & 15, kg = lane >> 4;
    int p0 = blockIdx.x * 64;
    int b = p0 >> 18;
    int hw0 = p0 & (PLANE - 1);
    int px = wva * 16 + cl;
    const unsigned* tp = t1b + (size_t)b * 32 * PLANE + hw0 + px;
    __syncthreads();

    // ---- B-frags for GEMM1: packed bf16 pairs direct from t1b ----
    unsigned bfr[2][4];
    #pragma unroll
    for (int ks = 0; ks < 2; ++ks)
        #pragma unroll
        for (int jp = 0; jp < 4; ++jp)
            bfr[ks][jp] = tp[(size_t)(ks * 16 + kg * 4 + jp) * PLANE];

    f32x4 acc[8];
    #pragma unroll
    for (int mt = 0; mt < 8; ++mt) acc[mt] = (f32x4){0.f, 0.f, 0.f, 0.f};
    #pragma unroll
    for (int ks = 0; ks < 2; ++ks) {
        union { unsigned u[4]; bf16x8 v; } bb;
        bb.u[0] = bfr[ks][0]; bb.u[1] = bfr[ks][1]; bb.u[2] = bfr[ks][2]; bb.u[3] = bfr[ks][3];
        #pragma unroll
        for (int mt = 0; mt < 8; ++mt) {
            bf16x8 af = *(const bf16x8*)(w1b + (size_t)(mt * 16 + cl) * 64 + ks * 32 + kg * 8);
            acc[mt] = __builtin_amdgcn_mfma_f32_16x16x32_bf16(af, bb.v, acc[mt], 0, 0, 0);
        }
    }

    // ---- vin (ch 64..127): bias+gelu -> bf16 LDS [px][ch] ----
    #pragma unroll
    for (int mt = 4; mt < 8; ++mt) {
        float g[4];
        #pragma unroll
        for (int r = 0; r < 4; ++r)
            g[r] = gelu_f(acc[mt][r] + pbl[mt * 16 + kg * 4 + r]);
        unsigned r01, r23;
        asm("v_cvt_pk_bf16_f32 %0,%1,%2" : "=v"(r01) : "v"(g[0]), "v"(g[1]));
        asm("v_cvt_pk_bf16_f32 %0,%1,%2" : "=v"(r23) : "v"(g[2]), "v"(g[3]));
        int ch = (mt - 4) * 16 + kg * 4;
        *(unsigned*)&vin[px][ch]     = r01;
        *(unsigned*)&vin[px][ch + 2] = r23;
    }

    // ---- k_in (ch 0..63): bias+gelu -> LDS transpose -> coalesced bf16 stores ----
    __syncthreads();
    #pragma unroll
    for (int mt = 0; mt < 4; ++mt)
        #pragma unroll
        for (int r = 0; r < 4; ++r) {
            int m = mt * 16 + kg * 4 + r;
            epi[m * 68 + px] = gelu_f(acc[mt][r] + pbl[m]);
        }
    __syncthreads();
    unsigned short* kb = k_in + (size_t)b * 64 * PLANE + hw0;
    #pragma unroll
    for (int k = 0; k < 4; ++k) {
        int m = wva * 16 + k * 4 + kg;
        float4 vv = *(const float4*)&epi[m * 68 + cl * 4];
        unsigned r01, r23;
        asm("v_cvt_pk_bf16_f32 %0,%1,%2" : "=v"(r01) : "v"(vv.x), "v"(vv.y));
        asm("v_cvt_pk_bf16_f32 %0,%1,%2" : "=v"(r23) : "v"(vv.z), "v"(vv.w));
        uint2 st; st.x = r01; st.y = r23;
        *(uint2*)&kb[(size_t)m * PLANE + cl * 4] = st;
    }

    // ---- GEMM2: v = W2 @ vin ----
    f32x4 acc2[8];
    #pragma unroll
    for (int mt = 0; mt < 8; ++mt) acc2[mt] = (f32x4){0.f, 0.f, 0.f, 0.f};
    #pragma unroll
    for (int ks = 0; ks < 2; ++ks) {
        bf16x8 bb = *(const bf16x8*)&vin[px][ks * 32 + kg * 8];
        #pragma unroll
        for (int mt = 0; mt < 8; ++mt) {
            bf16x8 af = *(const bf16x8*)(w2b + (size_t)(mt * 16 + cl) * 64 + ks * 32 + kg * 8);
            acc2[mt] = __builtin_amdgcn_mfma_f32_16x16x32_bf16(af, bb, acc2[mt], 0, 0, 0);
        }
    }

    // ---- v epilogue: BN + LDS transpose -> paired-channel uint planes ----
    unsigned* vpb = vp + (size_t)b * 64 * PLANE + hw0;
    #pragma unroll
    for (int pass = 0; pass < 2; ++pass) {
        __syncthreads();
        #pragma unroll
        for (int mt = pass * 4; mt < pass * 4 + 4; ++mt)
            #pragma unroll
            for (int r = 0; r < 4; ++r) {
                int m = mt * 16 + kg * 4 + r;
                epi[(m - pass * 64) * 68 + px] = acc2[mt][r] * psl[m] + ptl[m];
            }
        __syncthreads();
        #pragma unroll
        for (int it = 0; it < 2; ++it) {
            int idx = it * 256 + tid;
            int pr = idx >> 4;         // pair 0..31 within pass
            int seg = idx & 15;        // px group of 4
            const float* lo = &epi[(2 * pr) * 68 + seg * 4];
            const float* hi = &epi[(2 * pr + 1) * 68 + seg * 4];
            unsigned u0, u1, u2, u3;
            asm("v_cvt_pk_bf16_f32 %0,%1,%2" : "=v"(u0) : "v"(lo[0]), "v"(hi[0]));
            asm("v_cvt_pk_bf16_f32 %0,%1,%2" : "=v"(u1) : "v"(lo[1]), "v"(hi[1]));
            asm("v_cvt_pk_bf16_f32 %0,%1,%2" : "=v"(u2) : "v"(lo[2]), "v"(hi[2]));
            asm("v_cvt_pk_bf16_f32 %0,%1,%2" : "=v"(u3) : "v"(lo[3]), "v"(hi[3]));
            uint4 st; st.x = u0; st.y = u1; st.z = u2; st.w = u3;
            *(uint4*)&vpb[(size_t)(pass * 32 + pr) * PLANE + seg * 4] = st;
        }
    }
}

// ---------------- K4/K5: grouped dw 3x3 + BN + GELU pooled sums; 64 rows/block ----
template<typename T>
__global__ __launch_bounds__(512) void k_dwpool(const T* __restrict__ in,
                                                const float* __restrict__ wt,
                                                const float* __restrict__ bns,
                                                const float* __restrict__ bnt,
                                                float* __restrict__ rowsum,
                                                float* __restrict__ colpart) {
    __shared__ float lred[2][64][8];
    int tid = threadIdx.x;
    int blk = blockIdx.x;            // b*512 + g*8 + hc
    int hc = blk & 7;
    int g  = (blk >> 3) & 63;
    int b  = blk >> 9;
    int o0 = 2 * g, o1 = o0 + 1;
    const T* ip = in + ((size_t)b * 64 + g) * PLANE;
    float w0[9], w1[9];
    #pragma unroll
    for (int k = 0; k < 9; ++k) { w0[k] = wt[o0 * 9 + k]; w1[k] = wt[o1 * 9 + k]; }
    float s0 = bns[o0], t0 = bnt[o0], s1 = bns[o1], tt1 = bnt[o1];
    int w = tid;
    int wm = (w > 0)   ? w - 1 : w;  float vm0 = (w > 0)   ? 1.f : 0.f;
    int wp = (w < 511) ? w + 1 : w;  float vm2 = (w < 511) ? 1.f : 0.f;
    int h0 = hc * 64;
    int lane = tid & 63, wv = tid >> 6;
    float a0, a1, a2, r0, r1, r2, c0, c1, c2;
    if (h0 >= 1) {
        int o = (h0 - 1) * 512;
        a0 = ldval(ip, o + wm) * vm0; a1 = ldval(ip, o + w); a2 = ldval(ip, o + wp) * vm2;
    } else { a0 = a1 = a2 = 0.f; }
    {
        int o = h0 * 512;
        r0 = ldval(ip, o + wm) * vm0; r1 = ldval(ip, o + w); r2 = ldval(ip, o + wp) * vm2;
    }
    float ca0 = 0.f, ca1 = 0.f;
    for (int r = 0; r < 64; ++r) {
        int h = h0 + r;
        if (h + 1 <= 511) {
            int o = (h + 1) * 512;
            c0 = ldval(ip, o + wm) * vm0; c1 = ldval(ip, o + w); c2 = ldval(ip, o + wp) * vm2;
        } else { c0 = c1 = c2 = 0.f; }
        float x0 = w0[0]*a0 + w0[1]*a1 + w0[2]*a2 + w0[3]*r0 + w0[4]*r1 + w0[5]*r2
                 + w0[6]*c0 + w0[7]*c1 + w0[8]*c2;
        float x1 = w1[0]*a0 + w1[1]*a1 + w1[2]*a2 + w1[3]*r0 + w1[4]*r1 + w1[5]*r2
                 + w1[6]*c0 + w1[7]*c1 + w1[8]*c2;
        x0 = gelu_f(x0 * s0 + t0);
        x1 = gelu_f(x1 * s1 + tt1);
        ca0 += x0; ca1 += x1;
        #pragma unroll
        for (int off = 32; off > 0; off >>= 1) {
            x0 += __shfl_down(x0, off, 64);
            x1 += __shfl_down(x1, off, 64);
        }
        if (lane == 0) { lred[0][r][wv] = x0; lred[1][r][wv] = x1; }
        a0 = r0; a1 = r1; a2 = r2; r0 = c0; r1 = c1; r2 = c2;
    }
    colpart[((size_t)(b * 128 + o0) * 8 + hc) * 512 + w] = ca0;
    colpart[((size_t)(b * 128 + o1) * 8 + hc) * 512 + w] = ca1;
    __syncthreads();
    if (tid < 128) {
        int oo = tid >> 6, r = tid & 63;
        float s = 0.f;
        #pragma unroll
        for (int i = 0; i < 8; ++i) s += lred[oo][r][i];
        int och = oo ? o1 : o0;
        rowsum[((size_t)b * 128 + och) * 512 + h0 + r] = s;
    }
}

// ---------------- v pooling (paired uint planes): 64 rows/block ----------------
__global__ __launch_bounds__(512) void k_vpool(const unsigned* __restrict__ vp,
                                               float* __restrict__ rowsum,
                                               float* __restrict__ colpart) {
    __shared__ float lred[2][64][8];
    int tid = threadIdx.x;
    int blk = blockIdx.x;            // b*512 + c2*8 + hc
    int hc = blk & 7;
    int c2 = (blk >> 3) & 63;
    int b  = blk >> 9;
    const unsigned* ip = vp + ((size_t)b * 64 + c2) * PLANE;
    int h0 = hc * 64;
    int lane = tid & 63, wv = tid >> 6;
    float ca0 = 0.f, ca1 = 0.f;
    for (int r = 0; r < 64; ++r) {
        unsigned u = ip[(h0 + r) * 512 + tid];
        float a0 = bf2f((unsigned short)u);
        float a1 = bf2f((unsigned short)(u >> 16));
        ca0 += a0; ca1 += a1;
        #pragma unroll
        for (int off = 32; off > 0; off >>= 1) {
            a0 += __shfl_down(a0, off, 64);
            a1 += __shfl_down(a1, off, 64);
        }
        if (lane == 0) { lred[0][r][wv] = a0; lred[1][r][wv] = a1; }
    }
    colpart[((size_t)(b * 128 + 2 * c2)     * 8 + hc) * 512 + tid] = ca0;
    colpart[((size_t)(b * 128 + 2 * c2 + 1) * 8 + hc) * 512 + tid] = ca1;
    __syncthreads();
    if (tid < 128) {
        int oo = tid >> 6, r = tid & 63;
        float s = 0.f;
        #pragma unroll
        for (int i = 0; i < 8; ++i) s += lred[oo][r][i];
        rowsum[((size_t)b * 128 + 2 * c2 + oo) * 512 + h0 + r] = s;
    }
}

// ---------------- reduce col partials (merged q/k/v, 8-way) ----------------
__global__ __launch_bounds__(256) void k_colreduce(const float* __restrict__ part,
                                                   float* __restrict__ out, int n) {
    int idx = blockIdx.x * 256 + threadIdx.x;
    if (idx >= n) return;
    int bc = idx >> 9, w = idx & 511;
    const float* pp = part + ((size_t)bc * 8) * 512 + w;
    float s = 0.f;
    #pragma unroll
    for (int p = 0; p < 8; ++p) s += pp[p * 512];
    out[idx] = s;
}

// ---------------- K6: axial attention, one block per (b,axis,head,query-row i) ----
__global__ __launch_bounds__(256) void k_attn(const float* __restrict__ qrow,
                                              const float* __restrict__ krow,
                                              const float* __restrict__ vrow,
                                              const float* __restrict__ qcol,
                                              const float* __restrict__ kcol,
                                              const float* __restrict__ vcol,
                                              const float* __restrict__ perq,
                                              const float* __restrict__ perk,
                                              const float* __restrict__ pecq,
                                              const float* __restrict__ peck,
                                              float* __restrict__ arow,
                                              float* __restrict__ acol) {
    __shared__ float Pj[16];
    __shared__ float Pe[16];
    int blk = blockIdx.x;            // i | head<<4 | axis<<7 | b<<8
    int i    = blk & 15;
    int head = (blk >> 4) & 7;
    int axis = (blk >> 7) & 1;
    int b    = blk >> 8;
    const float* qs = axis ? qcol : qrow;
    const float* ks = axis ? kcol : krow;
    const float* vs = axis ? vcol : vrow;
    const float* peq = axis ? pecq : perq;
    const float* pek = axis ? peck : perk;
    float* out = axis ? acol : arow;
    int tid = threadIdx.x;
    int j = tid >> 4, l = tid & 15;
    int ci = head * 16 + i, cj = head * 16 + j;
    const float* qp = qs + ((size_t)b * 128 + ci) * 512;
    const float* kp = ks + ((size_t)b * 128 + cj) * 512;
    const float* qe = peq + ci * 512;
    const float* ke = pek + cj * 512;
    float s = 0.f;
    int n0 = l * 32;
    for (int n = n0; n < n0 + 32; ++n) {
        float qv = qp[n] * (1.f / 512.f) + qe[n];
        float kv = kp[n] * (1.f / 512.f) + ke[n];
        s = fmaf(qv, kv, s);
    }
    #pragma unroll
    for (int off = 8; off > 0; off >>= 1) s += __shfl_down(s, off, 16);
    if (l == 0) Pj[j] = s * 0.0441941738241592203f;   // 1/sqrt(512)
    __syncthreads();
    if (tid < 16) {
        float mx = -1e30f;
        #pragma unroll
        for (int jj = 0; jj < 16; ++jj) mx = fmaxf(mx, Pj[jj]);
        Pe[tid] = expf(Pj[tid] - mx);
    }
    __syncthreads();
    float sum = 0.f;
    #pragma unroll
    for (int jj = 0; jj < 16; ++jj) sum += Pe[jj];
    float inv = (1.f / 512.f) / sum;
    const float* vb = vs + ((size_t)b * 128 + head * 16) * 512;
    float* op = out + ((size_t)b * 128 + ci) * 512;
    #pragma unroll
    for (int rep = 0; rep < 2; ++rep) {
        int n = rep * 256 + tid;
        float acc = 0.f;
        #pragma unroll
        for (int jj = 0; jj < 16; ++jj)
            acc = fmaf(Pe[jj], vb[jj * 512 + n], acc);
        op[n] = acc * inv;
    }
}

// ---------------- setup: shuffled pw weights -> bf16 ----------------
__global__ __launch_bounds__(256) void k_wsetup(const float* __restrict__ pww,
                                                unsigned short* __restrict__ wsh) {
    int tid = blockIdx.x * 256 + threadIdx.x;
    if (tid >= 64 * 320) return;
    int m = tid / 320, src = tid % 320;
    int o = (src % 5) * 64 + src / 5;
    wsh[m * 320 + src] = f2bf(pww[m * 320 + o]);
}

// ---------------- setup: attn fold map AW[b][c][col] ----------------
__global__ __launch_bounds__(256) void k_awsetup(const float* __restrict__ pdw,
                                                 const float* __restrict__ aprw,
                                                 const float* __restrict__ apcw,
                                                 const float* __restrict__ arow,
                                                 const float* __restrict__ acol,
                                                 float* __restrict__ aw) {
    int idx = blockIdx.x * 256 + threadIdx.x;
    if (idx >= 2 * 128 * 512) return;
    int col = idx & 511;
    int c   = (idx >> 9) & 127;
    int b   = idx >> 16;
    int src = 64 + c;
    int o = (src % 5) * 64 + src / 5;
    const float* wd = pdw + o * 9;
    float ws0 = wd[0] + wd[3] + wd[6];
    float ws1 = wd[1] + wd[4] + wd[7];
    float ws2 = wd[2] + wd[5] + wd[8];
    const float* ar = arow + ((size_t)b * 128 + c) * 512;
    const float* ac = acol + ((size_t)b * 128 + c) * 512;
    float apr = aprw[c], apc = apcw[c];
    float sum = ws1 * (apr * ar[col] + apc * ac[col]);
    if (col > 0)   sum += ws0 * (apr * ar[col - 1] + apc * ac[col - 1]);
    if (col < 511) sum += ws2 * (apr * ar[col + 1] + apc * ac[col + 1]);
    aw[idx] = sum;
}

// ---------------- K7 v6: strip-of-2 frag-direct conv + MFMA; paired-channel v taps ----
// dual-pair conv: one uint tap load serves channels c (lo) and c+1 (hi); 4 weight
// sets (A/P for both channels) share 12 loads per pair.
template<bool HE, bool WE>
__device__ __forceinline__ void conv4x2b(const unsigned* __restrict__ p,
    const float* wA0, const float* wP0, const float* wA1, const float* wP1,
    const int* hrow, const float* rv, int ls, int rs, float cv0, float cv2,
    float oA[2][2], float oP[2][2])     // [e][hs]
{
    float aL0,aC0,aR0, aL1,aC1,aR1;
    float bL0,bC0,bR0, bL1,bC1,bR1;
    float cL0,cC0,cR0, cL1,cC1,cR1;
    const unsigned* q;
#define LDROW(L0,C0,R0,L1,C1,R1) do { \
        unsigned uL = WE ? q[ls] : q[-1]; \
        unsigned uC = q[0]; \
        unsigned uR = WE ? q[rs] : q[1]; \
        L0 = bf2f((unsigned short)uL); L1 = bf2f((unsigned short)(uL >> 16)); \
        C0 = bf2f((unsigned short)uC); C1 = bf2f((unsigned short)(uC >> 16)); \
        R0 = bf2f((unsigned short)uR); R1 = bf2f((unsigned short)(uR >> 16)); \
        if (WE) { L0 *= cv0; L1 *= cv0; R0 *= cv2; R1 *= cv2; } \
    } while (0)
    q = p + hrow[0] * 512; LDROW(aL0,aC0,aR0,aL1,aC1,aR1);
    q = p + hrow[1] * 512; LDROW(bL0,bC0,bR0,bL1,bC1,bR1);
    q = p + hrow[2] * 512; LDROW(cL0,cC0,cR0,cL1,cC1,cR1);
    #pragma unroll
    for (int hs = 0; hs < 2; ++hs) {
        float tA0 = wA0[0]*aL0 + wA0[1]*aC0 + wA0[2]*aR0;
        float mA0 = wA0[3]*bL0 + wA0[4]*bC0 + wA0[5]*bR0;
        float dA0 = wA0[6]*cL0 + wA0[7]*cC0 + wA0[8]*cR0;
        float tP0 = wP0[0]*aL0 + wP0[1]*aC0 + wP0[2]*aR0;
        float mP0 = wP0[3]*bL0 + wP0[4]*bC0 + wP0[5]*bR0;
        float dP0 = wP0[6]*cL0 + wP0[7]*cC0 + wP0[8]*cR0;
        float tA1 = wA1[0]*aL1 + wA1[1]*aC1 + wA1[2]*aR1;
        float mA1 = wA1[3]*bL1 + wA1[4]*bC1 + wA1[5]*bR1;
        float dA1 = wA1[6]*cL1 + wA1[7]*cC1 + wA1[8]*cR1;
        float tP1 = wP1[0]*aL1 + wP1[1]*aC1 + wP1[2]*aR1;
        float mP1 = wP1[3]*bL1 + wP1[4]*bC1 + wP1[5]*bR1;
        float dP1 = wP1[6]*cL1 + wP1[7]*cC1 + wP1[8]*cR1;
        if (HE) {
            oA[0][hs] = rv[hs]*tA0 + mA0 + rv[hs+2]*dA0 + wA0[9];
            oP[0][hs] = rv[hs]*tP0 + mP0 + rv[hs+2]*dP0 + wP0[9];
            oA[1][hs] = rv[hs]*tA1 + mA1 + rv[hs+2]*dA1 + wA1[9];
            oP[1][hs] = rv[hs]*tP1 + mP1 + rv[hs+2]*dP1 + wP1[9];
        } else {
            oA[0][hs] = tA0 + mA0 + dA0 + wA0[9];
            oP[0][hs] = tP0 + mP0 + dP0 + wP0[9];
            oA[1][hs] = tA1 + mA1 + dA1 + wA1[9];
            oP[1][hs] = tP1 + mP1 + dP1 + wP1[9];
        }
        if (hs < 1) {
            aL0=bL0; aC0=bC0; aR0=bR0; aL1=bL1; aC1=bC1; aR1=bR1;
            bL0=cL0; bC0=cC0; bR0=cR0; bL1=cL1; bC1=cC1; bR1=cR1;
            q = p + hrow[3] * 512; LDROW(cL0,cC0,cR0,cL1,cC1,cR1);
        }
    }
#undef LDROW
}

template<bool HE, bool WE>
__device__ __forceinline__ void conv1x2(const float* __restrict__ p,
    const float* wl,
    const int* hrow, const float* rv, int ls, int rs, float cv0, float cv2,
    float out[2])
{
    float a0,a1,a2, b0,b1,b2, c0,c1,c2;
    const float* q = p + hrow[0]*512;
    if (WE) { a0=q[ls]*cv0; a1=q[0]; a2=q[rs]*cv2; } else { a0=q[-1]; a1=q[0]; a2=q[1]; }
    q = p + hrow[1]*512;
    if (WE) { b0=q[ls]*cv0; b1=q[0]; b2=q[rs]*cv2; } else { b0=q[-1]; b1=q[0]; b2=q[1]; }
    q = p + hrow[2]*512;
    if (WE) { c0=q[ls]*cv0; c1=q[0]; c2=q[rs]*cv2; } else { c0=q[-1]; c1=q[0]; c2=q[1]; }
    #pragma unroll
    for (int hs = 0; hs < 2; ++hs) {
        float s0 = wl[0]*a0 + wl[1]*a1 + wl[2]*a2;
        float s1 = wl[3]*b0 + wl[4]*b1 + wl[5]*b2;
        float s2 = wl[6]*c0 + wl[7]*c1 + wl[8]*c2;
        out[hs] = (HE ? (rv[hs]*s0 + s1 + rv[hs+2]*s2) : (s0 + s1 + s2)) + wl[9];
        if (hs < 1) {
            a0=b0; a1=b1; a2=b2; b0=c0; b1=c1; b2=c2;
            q = p + hrow[3]*512;
            if (WE) { c0=q[ls]*cv0; c1=q[0]; c2=q[rs]*cv2; } else { c0=q[-1]; c1=q[0]; c2=q[1]; }
        }
    }
}

template<bool HE, bool WE>
__device__ __forceinline__ void proj5_core(
    int h0, int wwbase, float* epi, const float* dwl,
    const float* __restrict__ xb, const unsigned* __restrict__ vbp,
    const float* __restrict__ arb, const float* __restrict__ acb,
    const float* __restrict__ aprw, const float* __restrict__ apcw,
    const float* __restrict__ awb,
    const unsigned short* __restrict__ wsh, const float* __restrict__ pwb,
    float* __restrict__ outb)
{
    int tid = threadIdx.x;
    int lane = tid & 63, wva = tid >> 6;
    int cl = lane & 15, kg = lane >> 4;
    int ww = wwbase + wva * 16 + cl;

    int hrow[4]; float rv[4];
    #pragma unroll
    for (int i = 0; i < 4; ++i) {
        int r = h0 - 1 + i;
        float va = 1.f;
        if (HE) { if (r < 0) { r = 0; va = 0.f; } if (r > 511) { r = 511; va = 0.f; } }
        hrow[i] = r; rv[i] = va;
    }
    int ls = -1, rs = 1; float cv0 = 1.f, cv2 = 1.f;
    if (WE) {
        if (ww == 0)   { ls = 1;  cv0 = 0.f; }
        if (ww == 511) { rs = -1; cv2 = 0.f; }
    }

    f32x4 acc[2][4];
    #pragma unroll
    for (int hs = 0; hs < 2; ++hs)
        #pragma unroll
        for (int mt = 0; mt < 4; ++mt)
            acc[hs][mt] = (f32x4){0.f, 0.f, 0.f, 0.f};

    // ---- x slices (ks 0,1) ----
    #pragma unroll
    for (int ks = 0; ks < 2; ++ks) {
        unsigned bp[2][4];
        #pragma unroll
        for (int jp = 0; jp < 4; ++jp) {
            float cj0[2], cj1[2];
            int ch = ks * 32 + kg * 8 + jp * 2;
            conv1x2<HE,WE>(xb + (size_t)ch * PLANE + ww, dwl + ch * 12,
                           hrow, rv, ls, rs, cv0, cv2, cj0);
            conv1x2<HE,WE>(xb + (size_t)(ch+1) * PLANE + ww, dwl + (ch+1) * 12,
                           hrow, rv, ls, rs, cv0, cv2, cj1);
            #pragma unroll
            for (int hs = 0; hs < 2; ++hs) {
                float g0 = gelu_f(cj0[hs]), g1 = gelu_f(cj1[hs]);
                unsigned r;
                asm("v_cvt_pk_bf16_f32 %0,%1,%2" : "=v"(r) : "v"(g0), "v"(g1));
                bp[hs][jp] = r;
            }
        }
        #pragma unroll
        for (int mt = 0; mt < 4; ++mt) {
            bf16x8 af = *(const bf16x8*)(wsh + (size_t)(mt * 16 + cl) * 320 + ks * 32 + kg * 8);
            #pragma unroll
            for (int hs = 0; hs < 2; ++hs) {
                union { unsigned u[4]; bf16x8 v; } bb;
                bb.u[0] = bp[hs][0]; bb.u[1] = bp[hs][1]; bb.u[2] = bp[hs][2]; bb.u[3] = bp[hs][3];
                acc[hs][mt] = __builtin_amdgcn_mfma_f32_16x16x32_bf16(af, bb.v, acc[hs][mt], 0, 0, 0);
            }
        }
    }

    // ---- v slices: fused attn (slice 2+vks) + plain (slice 6+vks), paired taps ----
    #pragma unroll
    for (int vks = 0; vks < 4; ++vks) {
        unsigned bpA[2][4], bpP[2][4];
        #pragma unroll
        for (int jp = 0; jp < 4; ++jp) {
            int c = vks * 32 + kg * 8 + jp * 2;
            int pr = c >> 1;
            float cA[2][2], cP[2][2];
            conv4x2b<HE,WE>(vbp + (size_t)pr * PLANE + ww,
                            dwl + (64 + c) * 12,  dwl + (192 + c) * 12,
                            dwl + (64 + c + 1) * 12, dwl + (192 + c + 1) * 12,
                            hrow, rv, ls, rs, cv0, cv2, cA, cP);
            #pragma unroll
            for (int e = 0; e < 2; ++e) {
                float awv = awb[(size_t)(c + e) * 512 + ww];
                #pragma unroll
                for (int hs = 0; hs < 2; ++hs) {
                    if (!HE) {
                        cA[e][hs] += awv;
                    } else {
                        if (rv[hs] + rv[hs + 2] == 2.f) {
                            cA[e][hs] += awv;
                        } else {
                            const float* wlA = dwl + (64 + c + e) * 12;
                            const float* arp = arb + (size_t)(c + e) * 512 + ww;
                            const float* acp = acb + (size_t)(c + e) * 512 + ww;
                            float apr = aprw[c + e], apc = apcw[c + e];
                            float aa0 = (apr * arp[ls] + apc * acp[ls]) * cv0;
                            float aa1 =  apr * arp[0]  + apc * acp[0];
                            float aa2 = (apr * arp[rs] + apc * acp[rs]) * cv2;
                            float wd0 = rv[hs]*wlA[0] + wlA[3] + rv[hs+2]*wlA[6];
                            float wd1 = rv[hs]*wlA[1] + wlA[4] + rv[hs+2]*wlA[7];
                            float wd2 = rv[hs]*wlA[2] + wlA[5] + rv[hs+2]*wlA[8];
                            cA[e][hs] += wd0*aa0 + wd1*aa1 + wd2*aa2;
                        }
                    }
                }
            }
            #pragma unroll
            for (int hs = 0; hs < 2; ++hs) {
                float gA0 = gelu_f(cA[0][hs]), gA1 = gelu_f(cA[1][hs]);
                float gP0 = gelu_f(cP[0][hs]), gP1 = gelu_f(cP[1][hs]);
                unsigned ra, rp;
                asm("v_cvt_pk_bf16_f32 %0,%1,%2" : "=v"(ra) : "v"(gA0), "v"(gA1));
                asm("v_cvt_pk_bf16_f32 %0,%1,%2" : "=v"(rp) : "v"(gP0), "v"(gP1));
                bpA[hs][jp] = ra; bpP[hs][jp] = rp;
            }
        }
        #pragma unroll
        for (int mt = 0; mt < 4; ++mt) {
            bf16x8 afA = *(const bf16x8*)(wsh + (size_t)(mt * 16 + cl) * 320 + (2 + vks) * 32 + kg * 8);
            #pragma unroll
            for (int hs = 0; hs < 2; ++hs) {
                union { unsigned u[4]; bf16x8 v; } bb;
                bb.u[0] = bpA[hs][0]; bb.u[1] = bpA[hs][1]; bb.u[2] = bpA[hs][2]; bb.u[3] = bpA[hs][3];
                acc[hs][mt] = __builtin_amdgcn_mfma_f32_16x16x32_bf16(afA, bb.v, acc[hs][mt], 0, 0, 0);
            }
            bf16x8 afP = *(const bf16x8*)(wsh + (size_t)(mt * 16 + cl) * 320 + (6 + vks) * 32 + kg * 8);
            #pragma unroll
            for (int hs = 0; hs < 2; ++hs) {
                union { unsigned u[4]; bf16x8 v; } bb;
                bb.u[0] = bpP[hs][0]; bb.u[1] = bpP[hs][1]; bb.u[2] = bpP[hs][2]; bb.u[3] = bpP[hs][3];
                acc[hs][mt] = __builtin_amdgcn_mfma_f32_16x16x32_bf16(afP, bb.v, acc[hs][mt], 0, 0, 0);
            }
        }
    }

    // ---- epilogue: LDS transpose -> 256B-contiguous float4 stores ----
    #pragma unroll
    for (int hs = 0; hs < 2; ++hs) {
        __syncthreads();
        #pragma unroll
        for (int mt = 0; mt < 4; ++mt)
            #pragma unroll
            for (int r = 0; r < 4; ++r) {
                int m = mt * 16 + kg * 4 + r;
                epi[m * 68 + wva * 16 + cl] = gelu_f(acc[hs][mt][r] + pwb[m]);
            }
        __syncthreads();
        #pragma unroll
        for (int k = 0; k < 4; ++k) {
            int m = wva * 16 + k * 4 + kg;
            float4 vv = *(const float4*)&epi[m * 68 + cl * 4];
            *(float4*)&outb[(size_t)m * PLANE + (size_t)(h0 + hs) * 512 + wwbase + cl * 4] = vv;
        }
    }
}

__global__ __launch_bounds__(256, 4) void k_proj5(
    const float* __restrict__ x, const unsigned* __restrict__ vp,
    const float* __restrict__ arow, const float* __restrict__ acol,
    const float* __restrict__ aprw, const float* __restrict__ apcw,
    const float* __restrict__ dww, const float* __restrict__ dwb,
    const unsigned short* __restrict__ wsh, const float* __restrict__ pwb,
    const float* __restrict__ aw, float* __restrict__ out)
{
    __shared__ float dwl[320 * 12];   // 15,360 B
    __shared__ float epi[64 * 68];    // 17,408 B
    int tid = threadIdx.x;
    for (int i = tid; i < 3200; i += 256) {
        int src = i / 10, k = i - src * 10;
        int o = (src % 5) * 64 + src / 5;
        dwl[src * 12 + k] = (k < 9) ? dww[o * 9 + k] : dwb[o];
    }
    __syncthreads();
    // XCD swizzle: contiguous strip chunks per XCD
    int flat = blockIdx.x;                 // 0..4095
    int nf = (flat & 7) * 512 + (flat >> 3);
    int bx = nf & 7;
    int s  = (nf >> 3) & 255;
    int b  = nf >> 11;
    int h0 = s * 2, wwbase = bx * 64;
    const float* xb  = x + (size_t)b * 64 * PLANE;
    const unsigned* vbp = vp + (size_t)b * 64 * PLANE;
    const float* arb = arow + (size_t)b * 128 * 512;
    const float* acb = acol + (size_t)b * 128 * 512;
    const float* awb = aw + (size_t)b * 128 * 512;
    float* outb = out + (size_t)b * 64 * PLANE;
    bool HEr = (s == 0) || (s == 255);
    bool WEr = (bx == 0) || (bx == 7);
    if (!HEr && !WEr)
        proj5_core<false,false>(h0, wwbase, epi, dwl, xb, vbp, arb, acb, aprw, apcw, awb, wsh, pwb, outb);
    else if (!HEr)
        proj5_core<false,true >(h0, wwbase, epi, dwl, xb, vbp, arb, acb, aprw, apcw, awb, wsh, pwb, outb);
    else
        proj5_core<true ,true >(h0, wwbase, epi, dwl, xb, vbp, arb, acb, aprw, apcw, awb, wsh, pwb, outb);
}

extern "C" void kernel_launch(void* const* d_in, const int* in_sizes, int n_in,
                              void* d_out, int out_size, void* d_ws, size_t ws_size,
                              hipStream_t stream) {
    const float* x    = (const float*)d_in[0];
    const float* sc   = (const float*)d_in[1];
    const float* lnw  = (const float*)d_in[2];
    const float* lnb  = (const float*)d_in[3];
    const float* ddw  = (const float*)d_in[4];
    const float* dbs  = (const float*)d_in[5];
    const float* dbt  = (const float*)d_in[6];
    const float* pw1  = (const float*)d_in[7];
    const float* pb1  = (const float*)d_in[8];
    const float* qdw  = (const float*)d_in[9];
    const float* qbs  = (const float*)d_in[10];
    const float* qbt  = (const float*)d_in[11];
    const float* kdw  = (const float*)d_in[12];
    const float* kbs  = (const float*)d_in[13];
    const float* kbt  = (const float*)d_in[14];
    const float* vpw  = (const float*)d_in[15];
    const float* vbs  = (const float*)d_in[16];
    const float* vbt  = (const float*)d_in[17];
    const float* pdw  = (const float*)d_in[18];
    const float* pdb  = (const float*)d_in[19];
    const float* ppw  = (const float*)d_in[20];
    const float* ppb  = (const float*)d_in[21];
    const float* perq = (const float*)d_in[22];
    const float* perk = (const float*)d_in[23];
    const float* pecq = (const float*)d_in[24];
    const float* peck = (const float*)d_in[25];
    const float* aprw = (const float*)d_in[26];
    const float* apcw = (const float*)d_in[27];

    // d_out doubles as scratch: k_in bf16 (k_pw2 -> k_dwpool), then final out (k_proj5).
    unsigned short* kin_b = (unsigned short*)d_out;   // 33.5M ushort = 67MB
    float* ws   = (float*)d_ws;
    float* bufB = ws;                    // t1b packed bf16 pairs, later col partials
    unsigned* vp_b = (unsigned*)(ws + 33554432);      // 33.5M uints: paired-channel v
    float* sm   = ws + 100663296;        // pooled vectors
    float* qrow = sm;
    float* krow = sm + 131072;
    float* vrow = sm + 262144;
    float* qcol = sm + 393216;
    float* kcol = sm + 524288;
    float* vcol = sm + 655360;
    float* arow = sm + 786432;
    float* acol = sm + 917504;
    unsigned short* wsh = (unsigned short*)(ws + 101711872);   // 20480 bf16
    float* aw   = ws + 101722112;        // attn fold map
    unsigned short* w1b = (unsigned short*)(ws + 101853184);   // 8192 bf16
    unsigned short* w2b = (unsigned short*)(ws + 101857280);   // 8192 bf16
    float* Pb   = ws + 101861376;        // ln rstd
    float* Qb   = ws + 102385664;        // ln -mu*rstd
    unsigned* t1b = (unsigned*)bufB;     // 16.7M uints packed bf16 t1 (dead after k_pw2)
    float* qcp  = bufB;                  // 8-chunk col partials alias t1b
    float* kcp  = bufB + 1048576;
    float* vcp  = bufB + 2097152;

    k_wsetup <<<80,   256, 0, stream>>>(ppw, wsh);
    k_wsetup2<<<32,   256, 0, stream>>>(pw1, vpw, w1b, w2b);
    k_lnstats<<<2048, 256, 0, stream>>>(sc, Pb, Qb);
    k_dw64ln <<<2048, 256, 0, stream>>>(sc, ddw, lnw, lnb, dbs, dbt, Pb, Qb, t1b);
    k_pw2    <<<8192, 256, 0, stream>>>(t1b, w1b, pb1, w2b, vbs, vbt, kin_b, vp_b);
    k_dwpool<unsigned short><<<1024, 512, 0, stream>>>(kin_b, kdw, kbs, kbt, krow, kcp);
    k_vpool  <<<1024, 512, 0, stream>>>(vp_b, vrow, vcp);
    k_dwpool<float><<<1024, 512, 0, stream>>>(x, qdw, qbs, qbt, qrow, qcp);
    k_colreduce<<<1536, 256, 0, stream>>>(qcp, qcol, 393216);
    k_attn   <<<512,  256, 0, stream>>>(qrow, krow, vrow, qcol, kcol, vcol,
                                        perq, perk, pecq, peck, arow, acol);
    k_awsetup<<<512,  256, 0, stream>>>(pdw, aprw, apcw, arow, acol, aw);
    k_proj5  <<<4096, 256, 0, stream>>>(x, vp_b, arow, acol, aprw, apcw,
                                        pdw, pdb, wsh, ppb, aw, (float*)d_out);
}

// Round 15
// 855.957 us; speedup vs baseline: 1.0159x; 1.0159x over previous
//
#include <hip/hip_runtime.h>
#include <math.h>

#define PLANE (512*512)

typedef short bf16x8 __attribute__((ext_vector_type(8)));
typedef float f32x4 __attribute__((ext_vector_type(4)));

// fast GELU (tanh form): gelu(x) = x * sigmoid(1.59577x + 0.071355x^3); |err vs erf| <= ~3e-4
__device__ __forceinline__ float gelu_f(float x) {
    float t2 = fmaf(x * x, 0.0713548162f, 1.5957691216f);
    float e = __expf(x * t2);
    float r = __builtin_amdgcn_rcpf(1.0f + e);
    return fmaf(-x, r, x);     // x - x/(1+e) = x * e/(1+e)
}

__device__ __forceinline__ unsigned short f2bf(float f) {
    union { float f; unsigned u; } v; v.f = f;
    unsigned r = v.u + 0x7FFFu + ((v.u >> 16) & 1u);
    return (unsigned short)(r >> 16);
}

__device__ __forceinline__ float bf2f(unsigned short u) {
    union { unsigned u; float f; } x; x.u = ((unsigned)u) << 16; return x.f;
}

__device__ __forceinline__ float ldval(const float* p, int off) { return p[off]; }
__device__ __forceinline__ float ldval(const unsigned short* p, int off) { return bf2f(p[off]); }

// ---------------- K1a: LayerNorm stats per pixel: P=rstd, Q=-mu*rstd ----------------
__global__ __launch_bounds__(256) void k_lnstats(const float* __restrict__ sc,
                                                 float* __restrict__ Pb,
                                                 float* __restrict__ Qb) {
    int p = blockIdx.x * 256 + threadIdx.x;      // 0 .. 524287
    int b = p >> 18;
    int hw = p & (PLANE - 1);
    const float* src = sc + (size_t)b * 64 * PLANE + hw;
    float sum = 0.f, sq = 0.f;
    #pragma unroll 8
    for (int c = 0; c < 64; ++c) {
        float v = src[(size_t)c * PLANE];
        sum += v; sq += v * v;
    }
    float mu = sum * (1.0f / 64.0f);
    float var = sq * (1.0f / 64.0f) - mu * mu;
    float rstd = rsqrtf(var + 1e-5f);
    Pb[p] = rstd;
    Qb[p] = -mu * rstd;
}

// ---------------- K1b: fused LN + depthwise 3x3 + BN + GELU -> packed bf16 t1 ----------------
__global__ __launch_bounds__(256) void k_dw64ln(const float* __restrict__ sc,
                                                const float* __restrict__ dww,
                                                const float* __restrict__ lnw,
                                                const float* __restrict__ lnb,
                                                const float* __restrict__ bns,
                                                const float* __restrict__ bnt,
                                                const float* __restrict__ Pb,
                                                const float* __restrict__ Qb,
                                                unsigned* __restrict__ t1b) {
    int p = blockIdx.x * 256 + threadIdx.x;      // pixel
    int b = p >> 18;
    int hw = p & (PLANE - 1);
    int h = hw >> 9, w = hw & 511;
    int tapoff[9]; float Pt[9], Qt[9], vm[9];
    const float* Pp = Pb + (size_t)b * PLANE;
    const float* Qp = Qb + (size_t)b * PLANE;
    #pragma unroll
    for (int dh = -1; dh <= 1; ++dh)
        #pragma unroll
        for (int dw = -1; dw <= 1; ++dw) {
            int k = (dh + 1) * 3 + dw + 1;
            int hh = h + dh, ww = w + dw;
            bool ok = (hh >= 0 && hh < 512 && ww >= 0 && ww < 512);
            int hc = ok ? hh : h, wc = ok ? ww : w;
            int off = hc * 512 + wc;
            tapoff[k] = off;
            vm[k] = ok ? 1.f : 0.f;
            Pt[k] = Pp[off]; Qt[k] = Qp[off];
        }
    const float* scb = sc + (size_t)b * 64 * PLANE;
    unsigned* ob = t1b + (size_t)b * 32 * PLANE + hw;
    for (int c2 = 0; c2 < 32; ++c2) {
        float g[2];
        #pragma unroll
        for (int e = 0; e < 2; ++e) {
            int c = c2 * 2 + e;
            const float* wp = dww + c * 9;
            const float* cp = scb + (size_t)c * PLANE;
            float conv = 0.f, wsum = 0.f;
            #pragma unroll
            for (int k = 0; k < 9; ++k) {
                float wv = wp[k];
                float raw = cp[tapoff[k]];
                conv = fmaf(wv, fmaf(raw, Pt[k], Qt[k]) * vm[k], conv);
                wsum = fmaf(wv, vm[k], wsum);
            }
            float a = lnw[c] * conv + lnb[c] * wsum;
            g[e] = gelu_f(a * bns[c] + bnt[c]);
        }
        unsigned r;
        asm("v_cvt_pk_bf16_f32 %0,%1,%2" : "=v"(r) : "v"(g[0]), "v"(g[1]));
        ob[(size_t)c2 * PLANE] = r;
    }
}

// ---------------- setup: pw weights W1/W2 -> bf16 ----------------
__global__ __launch_bounds__(256) void k_wsetup2(const float* __restrict__ W1,
                                                 const float* __restrict__ W2,
                                                 unsigned short* __restrict__ w1b,
                                                 unsigned short* __restrict__ w2b) {
    int tid = blockIdx.x * 256 + threadIdx.x;
    if (tid < 8192) { w1b[tid] = f2bf(W1[tid]); w2b[tid] = f2bf(W2[tid]); }
}

// ---------------- K3 v2: MFMA pw 64->128 (+bias+gelu) split; outputs bf16 k_in / v ----
__global__ __launch_bounds__(256, 4) void k_pw2(
    const unsigned* __restrict__ t1b,
    const unsigned short* __restrict__ w1b, const float* __restrict__ b1,
    const unsigned short* __restrict__ w2b,
    const float* __restrict__ vbs, const float* __restrict__ vbt,
    unsigned short* __restrict__ k_in, unsigned short* __restrict__ v)
{
    __shared__ unsigned short vin[64][88];   // [px][ch] bf16
    __shared__ float epi[64 * 68];
    __shared__ float psl[128], ptl[128], pbl[128];
    int tid = threadIdx.x;
    if (tid < 128) { psl[tid] = vbs[tid]; ptl[tid] = vbt[tid]; pbl[tid] = b1[tid]; }
    int lane = tid & 63, wva = tid >> 6;
    int cl = lane & 15, kg = lane >> 4;
    int p0 = blockIdx.x * 64;
    int b = p0 >> 18;
    int hw0 = p0 & (PLANE - 1);
    int px = wva * 16 + cl;
    const unsigned* tp = t1b + (size_t)b * 32 * PLANE + hw0 + px;
    __syncthreads();

    // ---- B-frags for GEMM1: packed bf16 pairs direct from t1b ----
    unsigned bfr[2][4];
    #pragma unroll
    for (int ks = 0; ks < 2; ++ks)
        #pragma unroll
        for (int jp = 0; jp < 4; ++jp)
            bfr[ks][jp] = tp[(size_t)(ks * 16 + kg * 4 + jp) * PLANE];

    f32x4 acc[8];
    #pragma unroll
    for (int mt = 0; mt < 8; ++mt) acc[mt] = (f32x4){0.f, 0.f, 0.f, 0.f};
    #pragma unroll
    for (int ks = 0; ks < 2; ++ks) {
        union { unsigned u[4]; bf16x8 v; } bb;
        bb.u[0] = bfr[ks][0]; bb.u[1] = bfr[ks][1]; bb.u[2] = bfr[ks][2]; bb.u[3] = bfr[ks][3];
        #pragma unroll
        for (int mt = 0; mt < 8; ++mt) {
            bf16x8 af = *(const bf16x8*)(w1b + (size_t)(mt * 16 + cl) * 64 + ks * 32 + kg * 8);
            acc[mt] = __builtin_amdgcn_mfma_f32_16x16x32_bf16(af, bb.v, acc[mt], 0, 0, 0);
        }
    }

    // ---- vin (ch 64..127): bias+gelu -> bf16 LDS [px][ch] ----
    #pragma unroll
    for (int mt = 4; mt < 8; ++mt) {
        float g[4];
        #pragma unroll
        for (int r = 0; r < 4; ++r)
            g[r] = gelu_f(acc[mt][r] + pbl[mt * 16 + kg * 4 + r]);
        unsigned r01, r23;
        asm("v_cvt_pk_bf16_f32 %0,%1,%2" : "=v"(r01) : "v"(g[0]), "v"(g[1]));
        asm("v_cvt_pk_bf16_f32 %0,%1,%2" : "=v"(r23) : "v"(g[2]), "v"(g[3]));
        int ch = (mt - 4) * 16 + kg * 4;
        *(unsigned*)&vin[px][ch]     = r01;
        *(unsigned*)&vin[px][ch + 2] = r23;
    }

    // ---- k_in (ch 0..63): bias+gelu -> LDS transpose -> coalesced bf16 stores ----
    __syncthreads();
    #pragma unroll
    for (int mt = 0; mt < 4; ++mt)
        #pragma unroll
        for (int r = 0; r < 4; ++r) {
            int m = mt * 16 + kg * 4 + r;
            epi[m * 68 + px] = gelu_f(acc[mt][r] + pbl[m]);
        }
    __syncthreads();
    unsigned short* kb = k_in + (size_t)b * 64 * PLANE + hw0;
    #pragma unroll
    for (int k = 0; k < 4; ++k) {
        int m = wva * 16 + k * 4 + kg;
        float4 vv = *(const float4*)&epi[m * 68 + cl * 4];
        unsigned r01, r23;
        asm("v_cvt_pk_bf16_f32 %0,%1,%2" : "=v"(r01) : "v"(vv.x), "v"(vv.y));
        asm("v_cvt_pk_bf16_f32 %0,%1,%2" : "=v"(r23) : "v"(vv.z), "v"(vv.w));
        uint2 st; st.x = r01; st.y = r23;
        *(uint2*)&kb[(size_t)m * PLANE + cl * 4] = st;
    }

    // ---- GEMM2: v = W2 @ vin ----
    f32x4 acc2[8];
    #pragma unroll
    for (int mt = 0; mt < 8; ++mt) acc2[mt] = (f32x4){0.f, 0.f, 0.f, 0.f};
    #pragma unroll
    for (int ks = 0; ks < 2; ++ks) {
        bf16x8 bb = *(const bf16x8*)&vin[px][ks * 32 + kg * 8];
        #pragma unroll
        for (int mt = 0; mt < 8; ++mt) {
            bf16x8 af = *(const bf16x8*)(w2b + (size_t)(mt * 16 + cl) * 64 + ks * 32 + kg * 8);
            acc2[mt] = __builtin_amdgcn_mfma_f32_16x16x32_bf16(af, bb, acc2[mt], 0, 0, 0);
        }
    }

    // ---- v epilogue: BN + LDS transpose -> bf16, two 64-ch passes ----
    unsigned short* vb = v + (size_t)b * 128 * PLANE + hw0;
    #pragma unroll
    for (int pass = 0; pass < 2; ++pass) {
        __syncthreads();
        #pragma unroll
        for (int mt = pass * 4; mt < pass * 4 + 4; ++mt)
            #pragma unroll
            for (int r = 0; r < 4; ++r) {
                int m = mt * 16 + kg * 4 + r;
                epi[(m - pass * 64) * 68 + px] = acc2[mt][r] * psl[m] + ptl[m];
            }
        __syncthreads();
        #pragma unroll
        for (int k = 0; k < 4; ++k) {
            int ml = wva * 16 + k * 4 + kg;
            float4 vv = *(const float4*)&epi[ml * 68 + cl * 4];
            unsigned r01, r23;
            asm("v_cvt_pk_bf16_f32 %0,%1,%2" : "=v"(r01) : "v"(vv.x), "v"(vv.y));
            asm("v_cvt_pk_bf16_f32 %0,%1,%2" : "=v"(r23) : "v"(vv.z), "v"(vv.w));
            uint2 st; st.x = r01; st.y = r23;
            *(uint2*)&vb[(size_t)(pass * 64 + ml) * PLANE + cl * 4] = st;
        }
    }
}

// ---------------- K4/K5: grouped dw 3x3 + BN + GELU pooled sums; 64 rows/block,
// rolling register taps (3 loads/row), 8 col-partials -------------
template<typename T>
__global__ __launch_bounds__(512) void k_dwpool(const T* __restrict__ in,
                                                const float* __restrict__ wt,
                                                const float* __restrict__ bns,
                                                const float* __restrict__ bnt,
                                                float* __restrict__ rowsum,
                                                float* __restrict__ colpart) {
    __shared__ float lred[2][64][8];
    int tid = threadIdx.x;
    int blk = blockIdx.x;            // b*512 + g*8 + hc
    int hc = blk & 7;
    int g  = (blk >> 3) & 63;
    int b  = blk >> 9;
    int o0 = 2 * g, o1 = o0 + 1;
    const T* ip = in + ((size_t)b * 64 + g) * PLANE;
    float w0[9], w1[9];
    #pragma unroll
    for (int k = 0; k < 9; ++k) { w0[k] = wt[o0 * 9 + k]; w1[k] = wt[o1 * 9 + k]; }
    float s0 = bns[o0], t0 = bnt[o0], s1 = bns[o1], tt1 = bnt[o1];
    int w = tid;
    int wm = (w > 0)   ? w - 1 : w;  float vm0 = (w > 0)   ? 1.f : 0.f;
    int wp = (w < 511) ? w + 1 : w;  float vm2 = (w < 511) ? 1.f : 0.f;
    int h0 = hc * 64;
    int lane = tid & 63, wv = tid >> 6;
    float a0, a1, a2, r0, r1, r2, c0, c1, c2;
    if (h0 >= 1) {
        int o = (h0 - 1) * 512;
        a0 = ldval(ip, o + wm) * vm0; a1 = ldval(ip, o + w); a2 = ldval(ip, o + wp) * vm2;
    } else { a0 = a1 = a2 = 0.f; }
    {
        int o = h0 * 512;
        r0 = ldval(ip, o + wm) * vm0; r1 = ldval(ip, o + w); r2 = ldval(ip, o + wp) * vm2;
    }
    float ca0 = 0.f, ca1 = 0.f;
    for (int r = 0; r < 64; ++r) {
        int h = h0 + r;
        if (h + 1 <= 511) {
            int o = (h + 1) * 512;
            c0 = ldval(ip, o + wm) * vm0; c1 = ldval(ip, o + w); c2 = ldval(ip, o + wp) * vm2;
        } else { c0 = c1 = c2 = 0.f; }
        float x0 = w0[0]*a0 + w0[1]*a1 + w0[2]*a2 + w0[3]*r0 + w0[4]*r1 + w0[5]*r2
                 + w0[6]*c0 + w0[7]*c1 + w0[8]*c2;
        float x1 = w1[0]*a0 + w1[1]*a1 + w1[2]*a2 + w1[3]*r0 + w1[4]*r1 + w1[5]*r2
                 + w1[6]*c0 + w1[7]*c1 + w1[8]*c2;
        x0 = gelu_f(x0 * s0 + t0);
        x1 = gelu_f(x1 * s1 + tt1);
        ca0 += x0; ca1 += x1;
        #pragma unroll
        for (int off = 32; off > 0; off >>= 1) {
            x0 += __shfl_down(x0, off, 64);
            x1 += __shfl_down(x1, off, 64);
        }
        if (lane == 0) { lred[0][r][wv] = x0; lred[1][r][wv] = x1; }
        a0 = r0; a1 = r1; a2 = r2; r0 = c0; r1 = c1; r2 = c2;
    }
    colpart[((size_t)(b * 128 + o0) * 8 + hc) * 512 + w] = ca0;
    colpart[((size_t)(b * 128 + o1) * 8 + hc) * 512 + w] = ca1;
    __syncthreads();
    if (tid < 128) {
        int oo = tid >> 6, r = tid & 63;
        float s = 0.f;
        #pragma unroll
        for (int i = 0; i < 8; ++i) s += lred[oo][r][i];
        int och = oo ? o1 : o0;
        rowsum[((size_t)b * 128 + och) * 512 + h0 + r] = s;
    }
}

// ---------------- v pooling (bf16): 64 rows/block, 8 col-partials ----------------
__global__ __launch_bounds__(512) void k_vpool(const unsigned short* __restrict__ v,
                                               float* __restrict__ rowsum,
                                               float* __restrict__ colpart) {
    __shared__ float lred[64][8];
    int tid = threadIdx.x;
    int blk = blockIdx.x;            // b*1024 + c*8 + hc
    int hc = blk & 7;
    int c  = (blk >> 3) & 127;
    int b  = blk >> 10;
    int bc = b * 128 + c;
    const unsigned short* ip = v + (size_t)bc * PLANE;
    int h0 = hc * 64;
    int lane = tid & 63, wv = tid >> 6;
    float ca = 0.f;
    for (int r = 0; r < 64; ++r) {
        float a = bf2f(ip[(h0 + r) * 512 + tid]);
        ca += a;
        #pragma unroll
        for (int off = 32; off > 0; off >>= 1) a += __shfl_down(a, off, 64);
        if (lane == 0) lred[r][wv] = a;
    }
    colpart[((size_t)bc * 8 + hc) * 512 + tid] = ca;
    __syncthreads();
    if (tid < 64) {
        float s = 0.f;
        #pragma unroll
        for (int i = 0; i < 8; ++i) s += lred[tid][i];
        rowsum[(size_t)bc * 512 + h0 + tid] = s;
    }
}

// ---------------- reduce col partials (merged q/k/v, 8-way) ----------------
__global__ __launch_bounds__(256) void k_colreduce(const float* __restrict__ part,
                                                   float* __restrict__ out, int n) {
    int idx = blockIdx.x * 256 + threadIdx.x;
    if (idx >= n) return;
    int bc = idx >> 9, w = idx & 511;
    const float* pp = part + ((size_t)bc * 8) * 512 + w;
    float s = 0.f;
    #pragma unroll
    for (int p = 0; p < 8; ++p) s += pp[p * 512];
    out[idx] = s;
}

// ---------------- K6: axial attention, one block per (b,axis,head,query-row i) ----
__global__ __launch_bounds__(256) void k_attn(const float* __restrict__ qrow,
                                              const float* __restrict__ krow,
                                              const float* __restrict__ vrow,
                                              const float* __restrict__ qcol,
                                              const float* __restrict__ kcol,
                                              const float* __restrict__ vcol,
                                              const float* __restrict__ perq,
                                              const float* __restrict__ perk,
                                              const float* __restrict__ pecq,
                                              const float* __restrict__ peck,
                                              float* __restrict__ arow,
                                              float* __restrict__ acol) {
    __shared__ float Pj[16];
    __shared__ float Pe[16];
    int blk = blockIdx.x;            // i | head<<4 | axis<<7 | b<<8
    int i    = blk & 15;
    int head = (blk >> 4) & 7;
    int axis = (blk >> 7) & 1;
    int b    = blk >> 8;
    const float* qs = axis ? qcol : qrow;
    const float* ks = axis ? kcol : krow;
    const float* vs = axis ? vcol : vrow;
    const float* peq = axis ? pecq : perq;
    const float* pek = axis ? peck : perk;
    float* out = axis ? acol : arow;
    int tid = threadIdx.x;
    int j = tid >> 4, l = tid & 15;
    int ci = head * 16 + i, cj = head * 16 + j;
    const float* qp = qs + ((size_t)b * 128 + ci) * 512;
    const float* kp = ks + ((size_t)b * 128 + cj) * 512;
    const float* qe = peq + ci * 512;
    const float* ke = pek + cj * 512;
    float s = 0.f;
    int n0 = l * 32;
    for (int n = n0; n < n0 + 32; ++n) {
        float qv = qp[n] * (1.f / 512.f) + qe[n];
        float kv = kp[n] * (1.f / 512.f) + ke[n];
        s = fmaf(qv, kv, s);
    }
    #pragma unroll
    for (int off = 8; off > 0; off >>= 1) s += __shfl_down(s, off, 16);
    if (l == 0) Pj[j] = s * 0.0441941738241592203f;   // 1/sqrt(512)
    __syncthreads();
    if (tid < 16) {
        float mx = -1e30f;
        #pragma unroll
        for (int jj = 0; jj < 16; ++jj) mx = fmaxf(mx, Pj[jj]);
        Pe[tid] = expf(Pj[tid] - mx);
    }
    __syncthreads();
    float sum = 0.f;
    #pragma unroll
    for (int jj = 0; jj < 16; ++jj) sum += Pe[jj];
    float inv = (1.f / 512.f) / sum;
    const float* vb = vs + ((size_t)b * 128 + head * 16) * 512;
    float* op = out + ((size_t)b * 128 + ci) * 512;
    #pragma unroll
    for (int rep = 0; rep < 2; ++rep) {
        int n = rep * 256 + tid;
        float acc = 0.f;
        #pragma unroll
        for (int jj = 0; jj < 16; ++jj)
            acc = fmaf(Pe[jj], vb[jj * 512 + n], acc);
        op[n] = acc * inv;
    }
}

// ---------------- setup: shuffled pw weights -> bf16 ----------------
__global__ __launch_bounds__(256) void k_wsetup(const float* __restrict__ pww,
                                                unsigned short* __restrict__ wsh) {
    int tid = blockIdx.x * 256 + threadIdx.x;
    if (tid >= 64 * 320) return;
    int m = tid / 320, src = tid % 320;
    int o = (src % 5) * 64 + src / 5;
    wsh[m * 320 + src] = f2bf(pww[m * 320 + o]);
}

// ---------------- setup: attn fold map AW[b][c][col] ----------------
__global__ __launch_bounds__(256) void k_awsetup(const float* __restrict__ pdw,
                                                 const float* __restrict__ aprw,
                                                 const float* __restrict__ apcw,
                                                 const float* __restrict__ arow,
                                                 const float* __restrict__ acol,
                                                 float* __restrict__ aw) {
    int idx = blockIdx.x * 256 + threadIdx.x;
    if (idx >= 2 * 128 * 512) return;
    int col = idx & 511;
    int c   = (idx >> 9) & 127;
    int b   = idx >> 16;
    int src = 64 + c;
    int o = (src % 5) * 64 + src / 5;
    const float* wd = pdw + o * 9;
    float ws0 = wd[0] + wd[3] + wd[6];
    float ws1 = wd[1] + wd[4] + wd[7];
    float ws2 = wd[2] + wd[5] + wd[8];
    const float* ar = arow + ((size_t)b * 128 + c) * 512;
    const float* ac = acol + ((size_t)b * 128 + c) * 512;
    float apr = aprw[c], apc = apcw[c];
    float sum = ws1 * (apr * ar[col] + apc * ac[col]);
    if (col > 0)   sum += ws0 * (apr * ar[col - 1] + apc * ac[col - 1]);
    if (col < 511) sum += ws2 * (apr * ar[col + 1] + apc * ac[col + 1]);
    aw[idx] = sum;
}

// ---------------- K7 v5: strip-of-2 frag-direct conv + MFMA + LDS-coalesced epilogue ----
template<bool HE, bool WE>
__device__ __forceinline__ void conv2x2b(const unsigned short* __restrict__ p,
    const float* wlA, const float* wlP,
    const int* hrow, const float* rv, int ls, int rs, float cv0, float cv2,
    float outA[2], float outP[2])
{
    float a0,a1,a2, b0,b1,b2, c0,c1,c2;
    const unsigned short* q = p + hrow[0]*512;
    if (WE) { a0=bf2f(q[ls])*cv0; a1=bf2f(q[0]); a2=bf2f(q[rs])*cv2; } else { a0=bf2f(q[-1]); a1=bf2f(q[0]); a2=bf2f(q[1]); }
    q = p + hrow[1]*512;
    if (WE) { b0=bf2f(q[ls])*cv0; b1=bf2f(q[0]); b2=bf2f(q[rs])*cv2; } else { b0=bf2f(q[-1]); b1=bf2f(q[0]); b2=bf2f(q[1]); }
    q = p + hrow[2]*512;
    if (WE) { c0=bf2f(q[ls])*cv0; c1=bf2f(q[0]); c2=bf2f(q[rs])*cv2; } else { c0=bf2f(q[-1]); c1=bf2f(q[0]); c2=bf2f(q[1]); }
    #pragma unroll
    for (int hs = 0; hs < 2; ++hs) {
        float sA0 = wlA[0]*a0 + wlA[1]*a1 + wlA[2]*a2;
        float sA1 = wlA[3]*b0 + wlA[4]*b1 + wlA[5]*b2;
        float sA2 = wlA[6]*c0 + wlA[7]*c1 + wlA[8]*c2;
        float sP0 = wlP[0]*a0 + wlP[1]*a1 + wlP[2]*a2;
        float sP1 = wlP[3]*b0 + wlP[4]*b1 + wlP[5]*b2;
        float sP2 = wlP[6]*c0 + wlP[7]*c1 + wlP[8]*c2;
        if (HE) {
            outA[hs] = rv[hs]*sA0 + sA1 + rv[hs+2]*sA2 + wlA[9];
            outP[hs] = rv[hs]*sP0 + sP1 + rv[hs+2]*sP2 + wlP[9];
        } else {
            outA[hs] = sA0 + sA1 + sA2 + wlA[9];
            outP[hs] = sP0 + sP1 + sP2 + wlP[9];
        }
        if (hs < 1) {
            a0=b0; a1=b1; a2=b2; b0=c0; b1=c1; b2=c2;
            q = p + hrow[3]*512;
            if (WE) { c0=bf2f(q[ls])*cv0; c1=bf2f(q[0]); c2=bf2f(q[rs])*cv2; } else { c0=bf2f(q[-1]); c1=bf2f(q[0]); c2=bf2f(q[1]); }
        }
    }
}

template<bool HE, bool WE>
__device__ __forceinline__ void conv1x2(const float* __restrict__ p,
    const float* wl,
    const int* hrow, const float* rv, int ls, int rs, float cv0, float cv2,
    float out[2])
{
    float a0,a1,a2, b0,b1,b2, c0,c1,c2;
    const float* q = p + hrow[0]*512;
    if (WE) { a0=q[ls]*cv0; a1=q[0]; a2=q[rs]*cv2; } else { a0=q[-1]; a1=q[0]; a2=q[1]; }
    q = p + hrow[1]*512;
    if (WE) { b0=q[ls]*cv0; b1=q[0]; b2=q[rs]*cv2; } else { b0=q[-1]; b1=q[0]; b2=q[1]; }
    q = p + hrow[2]*512;
    if (WE) { c0=q[ls]*cv0; c1=q[0]; c2=q[rs]*cv2; } else { c0=q[-1]; c1=q[0]; c2=q[1]; }
    #pragma unroll
    for (int hs = 0; hs < 2; ++hs) {
        float s0 = wl[0]*a0 + wl[1]*a1 + wl[2]*a2;
        float s1 = wl[3]*b0 + wl[4]*b1 + wl[5]*b2;
        float s2 = wl[6]*c0 + wl[7]*c1 + wl[8]*c2;
        out[hs] = (HE ? (rv[hs]*s0 + s1 + rv[hs+2]*s2) : (s0 + s1 + s2)) + wl[9];
        if (hs < 1) {
            a0=b0; a1=b1; a2=b2; b0=c0; b1=c1; b2=c2;
            q = p + hrow[3]*512;
            if (WE) { c0=q[ls]*cv0; c1=q[0]; c2=q[rs]*cv2; } else { c0=q[-1]; c1=q[0]; c2=q[1]; }
        }
    }
}

template<bool HE, bool WE>
__device__ __forceinline__ void proj5_core(
    int h0, int wwbase, float* epi, const float* dwl,
    const float* __restrict__ xb, const unsigned short* __restrict__ vbp,
    const float* __restrict__ arb, const float* __restrict__ acb,
    const float* __restrict__ aprw, const float* __restrict__ apcw,
    const float* __restrict__ awb,
    const unsigned short* __restrict__ wsh, const float* __restrict__ pwb,
    float* __restrict__ outb)
{
    int tid = threadIdx.x;
    int lane = tid & 63, wva = tid >> 6;
    int cl = lane & 15, kg = lane >> 4;
    int ww = wwbase + wva * 16 + cl;

    int hrow[4]; float rv[4];
    #pragma unroll
    for (int i = 0; i < 4; ++i) {
        int r = h0 - 1 + i;
        float va = 1.f;
        if (HE) { if (r < 0) { r = 0; va = 0.f; } if (r > 511) { r = 511; va = 0.f; } }
        hrow[i] = r; rv[i] = va;
    }
    int ls = -1, rs = 1; float cv0 = 1.f, cv2 = 1.f;
    if (WE) {
        if (ww == 0)   { ls = 1;  cv0 = 0.f; }
        if (ww == 511) { rs = -1; cv2 = 0.f; }
    }

    f32x4 acc[2][4];
    #pragma unroll
    for (int hs = 0; hs < 2; ++hs)
        #pragma unroll
        for (int mt = 0; mt < 4; ++mt)
            acc[hs][mt] = (f32x4){0.f, 0.f, 0.f, 0.f};

    // ---- x slices (ks 0,1) ----
    #pragma unroll
    for (int ks = 0; ks < 2; ++ks) {
        unsigned bp[2][4];
        #pragma unroll
        for (int jp = 0; jp < 4; ++jp) {
            float cj0[2], cj1[2];
            int ch = ks * 32 + kg * 8 + jp * 2;
            conv1x2<HE,WE>(xb + (size_t)ch * PLANE + ww, dwl + ch * 12,
                           hrow, rv, ls, rs, cv0, cv2, cj0);
            conv1x2<HE,WE>(xb + (size_t)(ch+1) * PLANE + ww, dwl + (ch+1) * 12,
                           hrow, rv, ls, rs, cv0, cv2, cj1);
            #pragma unroll
            for (int hs = 0; hs < 2; ++hs) {
                float g0 = gelu_f(cj0[hs]), g1 = gelu_f(cj1[hs]);
                unsigned r;
                asm("v_cvt_pk_bf16_f32 %0,%1,%2" : "=v"(r) : "v"(g0), "v"(g1));
                bp[hs][jp] = r;
            }
        }
        #pragma unroll
        for (int mt = 0; mt < 4; ++mt) {
            bf16x8 af = *(const bf16x8*)(wsh + (size_t)(mt * 16 + cl) * 320 + ks * 32 + kg * 8);
            #pragma unroll
            for (int hs = 0; hs < 2; ++hs) {
                union { unsigned u[4]; bf16x8 v; } bb;
                bb.u[0] = bp[hs][0]; bb.u[1] = bp[hs][1]; bb.u[2] = bp[hs][2]; bb.u[3] = bp[hs][3];
                acc[hs][mt] = __builtin_amdgcn_mfma_f32_16x16x32_bf16(af, bb.v, acc[hs][mt], 0, 0, 0);
            }
        }
    }

    // ---- v slices: fused attn (slice 2+vks) + plain (slice 6+vks), bf16 taps ----
    #pragma unroll
    for (int vks = 0; vks < 4; ++vks) {
        unsigned bpA[2][4], bpP[2][4];
        #pragma unroll
        for (int jp = 0; jp < 4; ++jp) {
            float cA[2][2], cP[2][2];
            #pragma unroll
            for (int e = 0; e < 2; ++e) {
                int c = vks * 32 + kg * 8 + jp * 2 + e;
                const float* wlA = dwl + (64 + c) * 12;
                conv2x2b<HE,WE>(vbp + (size_t)c * PLANE + ww, wlA, dwl + (192 + c) * 12,
                                hrow, rv, ls, rs, cv0, cv2, cA[e], cP[e]);
                float awv = awb[(size_t)c * 512 + ww];
                #pragma unroll
                for (int hs = 0; hs < 2; ++hs) {
                    if (!HE) {
                        cA[e][hs] += awv;
                    } else {
                        if (rv[hs] + rv[hs + 2] == 2.f) {
                            cA[e][hs] += awv;
                        } else {
                            const float* arp = arb + (size_t)c * 512 + ww;
                            const float* acp = acb + (size_t)c * 512 + ww;
                            float apr = aprw[c], apc = apcw[c];
                            float aa0 = (apr * arp[ls] + apc * acp[ls]) * cv0;
                            float aa1 =  apr * arp[0]  + apc * acp[0];
                            float aa2 = (apr * arp[rs] + apc * acp[rs]) * cv2;
                            float wd0 = rv[hs]*wlA[0] + wlA[3] + rv[hs+2]*wlA[6];
                            float wd1 = rv[hs]*wlA[1] + wlA[4] + rv[hs+2]*wlA[7];
                            float wd2 = rv[hs]*wlA[2] + wlA[5] + rv[hs+2]*wlA[8];
                            cA[e][hs] += wd0*aa0 + wd1*aa1 + wd2*aa2;
                        }
                    }
                }
            }
            #pragma unroll
            for (int hs = 0; hs < 2; ++hs) {
                float gA0 = gelu_f(cA[0][hs]), gA1 = gelu_f(cA[1][hs]);
                float gP0 = gelu_f(cP[0][hs]), gP1 = gelu_f(cP[1][hs]);
                unsigned ra, rp;
                asm("v_cvt_pk_bf16_f32 %0,%1,%2" : "=v"(ra) : "v"(gA0), "v"(gA1));
                asm("v_cvt_pk_bf16_f32 %0,%1,%2" : "=v"(rp) : "v"(gP0), "v"(gP1));
                bpA[hs][jp] = ra; bpP[hs][jp] = rp;
            }
        }
        #pragma unroll
        for (int mt = 0; mt < 4; ++mt) {
            bf16x8 afA = *(const bf16x8*)(wsh + (size_t)(mt * 16 + cl) * 320 + (2 + vks) * 32 + kg * 8);
            #pragma unroll
            for (int hs = 0; hs < 2; ++hs) {
                union { unsigned u[4]; bf16x8 v; } bb;
                bb.u[0] = bpA[hs][0]; bb.u[1] = bpA[hs][1]; bb.u[2] = bpA[hs][2]; bb.u[3] = bpA[hs][3];
                acc[hs][mt] = __builtin_amdgcn_mfma_f32_16x16x32_bf16(afA, bb.v, acc[hs][mt], 0, 0, 0);
            }
            bf16x8 afP = *(const bf16x8*)(wsh + (size_t)(mt * 16 + cl) * 320 + (6 + vks) * 32 + kg * 8);
            #pragma unroll
            for (int hs = 0; hs < 2; ++hs) {
                union { unsigned u[4]; bf16x8 v; } bb;
                bb.u[0] = bpP[hs][0]; bb.u[1] = bpP[hs][1]; bb.u[2] = bpP[hs][2]; bb.u[3] = bpP[hs][3];
                acc[hs][mt] = __builtin_amdgcn_mfma_f32_16x16x32_bf16(afP, bb.v, acc[hs][mt], 0, 0, 0);
            }
        }
    }

    // ---- epilogue: LDS transpose -> 256B-contiguous float4 stores ----
    #pragma unroll
    for (int hs = 0; hs < 2; ++hs) {
        __syncthreads();
        #pragma unroll
        for (int mt = 0; mt < 4; ++mt)
            #pragma unroll
            for (int r = 0; r < 4; ++r) {
                int m = mt * 16 + kg * 4 + r;
                epi[m * 68 + wva * 16 + cl] = gelu_f(acc[hs][mt][r] + pwb[m]);
            }
        __syncthreads();
        #pragma unroll
        for (int k = 0; k < 4; ++k) {
            int m = wva * 16 + k * 4 + kg;
            float4 vv = *(const float4*)&epi[m * 68 + cl * 4];
            *(float4*)&outb[(size_t)m * PLANE + (size_t)(h0 + hs) * 512 + wwbase + cl * 4] = vv;
        }
    }
}

__global__ __launch_bounds__(256, 4) void k_proj5(
    const float* __restrict__ x, const unsigned short* __restrict__ v,
    const float* __restrict__ arow, const float* __restrict__ acol,
    const float* __restrict__ aprw, const float* __restrict__ apcw,
    const float* __restrict__ dww, const float* __restrict__ dwb,
    const unsigned short* __restrict__ wsh, const float* __restrict__ pwb,
    const float* __restrict__ aw, float* __restrict__ out)
{
    __shared__ float dwl[320 * 12];   // 15,360 B
    __shared__ float epi[64 * 68];    // 17,408 B
    int tid = threadIdx.x;
    for (int i = tid; i < 3200; i += 256) {
        int src = i / 10, k = i - src * 10;
        int o = (src % 5) * 64 + src / 5;
        dwl[src * 12 + k] = (k < 9) ? dww[o * 9 + k] : dwb[o];
    }
    __syncthreads();
    // XCD swizzle: contiguous strip chunks per XCD
    int flat = blockIdx.x;                 // 0..4095
    int nf = (flat & 7) * 512 + (flat >> 3);
    int bx = nf & 7;
    int s  = (nf >> 3) & 255;
    int b  = nf >> 11;
    int h0 = s * 2, wwbase = bx * 64;
    const float* xb  = x + (size_t)b * 64 * PLANE;
    const unsigned short* vbp = v + (size_t)b * 128 * PLANE;
    const float* arb = arow + (size_t)b * 128 * 512;
    const float* acb = acol + (size_t)b * 128 * 512;
    const float* awb = aw + (size_t)b * 128 * 512;
    float* outb = out + (size_t)b * 64 * PLANE;
    bool HEr = (s == 0) || (s == 255);
    bool WEr = (bx == 0) || (bx == 7);
    if (!HEr && !WEr)
        proj5_core<false,false>(h0, wwbase, epi, dwl, xb, vbp, arb, acb, aprw, apcw, awb, wsh, pwb, outb);
    else if (!HEr)
        proj5_core<false,true >(h0, wwbase, epi, dwl, xb, vbp, arb, acb, aprw, apcw, awb, wsh, pwb, outb);
    else
        proj5_core<true ,true >(h0, wwbase, epi, dwl, xb, vbp, arb, acb, aprw, apcw, awb, wsh, pwb, outb);
}

extern "C" void kernel_launch(void* const* d_in, const int* in_sizes, int n_in,
                              void* d_out, int out_size, void* d_ws, size_t ws_size,
                              hipStream_t stream) {
    const float* x    = (const float*)d_in[0];
    const float* sc   = (const float*)d_in[1];
    const float* lnw  = (const float*)d_in[2];
    const float* lnb  = (const float*)d_in[3];
    const float* ddw  = (const float*)d_in[4];
    const float* dbs  = (const float*)d_in[5];
    const float* dbt  = (const float*)d_in[6];
    const float* pw1  = (const float*)d_in[7];
    const float* pb1  = (const float*)d_in[8];
    const float* qdw  = (const float*)d_in[9];
    const float* qbs  = (const float*)d_in[10];
    const float* qbt  = (const float*)d_in[11];
    const float* kdw  = (const float*)d_in[12];
    const float* kbs  = (const float*)d_in[13];
    const float* kbt  = (const float*)d_in[14];
    const float* vpw  = (const float*)d_in[15];
    const float* vbs  = (const float*)d_in[16];
    const float* vbt  = (const float*)d_in[17];
    const float* pdw  = (const float*)d_in[18];
    const float* pdb  = (const float*)d_in[19];
    const float* ppw  = (const float*)d_in[20];
    const float* ppb  = (const float*)d_in[21];
    const float* perq = (const float*)d_in[22];
    const float* perk = (const float*)d_in[23];
    const float* pecq = (const float*)d_in[24];
    const float* peck = (const float*)d_in[25];
    const float* aprw = (const float*)d_in[26];
    const float* apcw = (const float*)d_in[27];

    // d_out doubles as scratch: k_in bf16 (k_pw2 -> k_dwpool), then final out (k_proj5).
    unsigned short* kin_b = (unsigned short*)d_out;   // 33.5M ushort = 67MB
    float* ws   = (float*)d_ws;
    float* bufB = ws;                    // t1b packed bf16 pairs, later col partials
    unsigned short* v_b = (unsigned short*)(ws + 33554432);  // 33.5M ushort v (bf16)
    float* sm   = ws + 100663296;        // pooled vectors
    float* qrow = sm;
    float* krow = sm + 131072;
    float* vrow = sm + 262144;
    float* qcol = sm + 393216;
    float* kcol = sm + 524288;
    float* vcol = sm + 655360;
    float* arow = sm + 786432;
    float* acol = sm + 917504;
    unsigned short* wsh = (unsigned short*)(ws + 101711872);   // 20480 bf16
    float* aw   = ws + 101722112;        // attn fold map
    unsigned short* w1b = (unsigned short*)(ws + 101853184);   // 8192 bf16
    unsigned short* w2b = (unsigned short*)(ws + 101857280);   // 8192 bf16
    float* Pb   = ws + 101861376;        // ln rstd
    float* Qb   = ws + 102385664;        // ln -mu*rstd
    unsigned* t1b = (unsigned*)bufB;     // 16.7M uints packed bf16 t1 (dead after k_pw2)
    float* qcp  = bufB;                  // 8-chunk col partials alias t1b
    float* kcp  = bufB + 1048576;
    float* vcp  = bufB + 2097152;

    k_wsetup <<<80,   256, 0, stream>>>(ppw, wsh);
    k_wsetup2<<<32,   256, 0, stream>>>(pw1, vpw, w1b, w2b);
    k_lnstats<<<2048, 256, 0, stream>>>(sc, Pb, Qb);
    k_dw64ln <<<2048, 256, 0, stream>>>(sc, ddw, lnw, lnb, dbs, dbt, Pb, Qb, t1b);
    k_pw2    <<<8192, 256, 0, stream>>>(t1b, w1b, pb1, w2b, vbs, vbt, kin_b, v_b);
    k_dwpool<unsigned short><<<1024, 512, 0, stream>>>(kin_b, kdw, kbs, kbt, krow, kcp);
    k_vpool  <<<2048, 512, 0, stream>>>(v_b, vrow, vcp);
    k_dwpool<float><<<1024, 512, 0, stream>>>(x, qdw, qbs, qbt, qrow, qcp);
    k_colreduce<<<1536, 256, 0, stream>>>(qcp, qcol, 393216);
    k_attn   <<<512,  256, 0, stream>>>(qrow, krow, vrow, qcol, kcol, vcol,
                                        perq, perk, pecq, peck, arow, acol);
    k_awsetup<<<512,  256, 0, stream>>>(pdw, aprw, apcw, arow, acol, aw);
    k_proj5  <<<4096, 256, 0, stream>>>(x, v_b, arow, acol, aprw, apcw,
                                        pdw, pdb, wsh, ppb, aw, (float*)d_out);
}